// Round 12
// baseline (58.071 us; speedup 1.0000x reference)
//
#include <hip/hip_runtime.h>
#include <hip/hip_fp16.h>

// Damped electrostatics with shifted-force cutoff.
// Packed atom table in d_ws, 32 B/atom (3.2 MB, L2-resident per XCD):
//   word0 (f32x4): q, dip.x, dip.y, dip.z
//   word1 (u32x4): fp16x2{t00,t11}, fp16x2{t22,s01}, fp16x2{s02,s12}, pad
// Edge kernel: grid-stride, DEPTH-2 GATHER pipeline + depth-4 stream
// pipeline. Gathers are issued 2 iterations before use (~600+ cyc lead >
// L2 latency); idx streams are resident 2 iterations before their gather
// is issued. All prefetch indices clamp to E-1 (branchless, redundant
// loads discarded). d recomputed from vec (d == |v| by construction).

#define KEHALF      7.199822675975274f

typedef float    f32x4 __attribute__((ext_vector_type(4)));
typedef unsigned u32x4 __attribute__((ext_vector_type(4)));

#define NTL(p) __builtin_nontemporal_load(p)

__device__ __forceinline__ unsigned pack_h2(float a, float b) {
    return __builtin_bit_cast(unsigned, __floats2half2_rn(a, b));
}
__device__ __forceinline__ float2 unpack_h2(unsigned u) {
    return __half22float2(__builtin_bit_cast(__half2, u));
}

__global__ __launch_bounds__(256) void pack_atoms_kernel(
    const float* __restrict__ q,
    const float* __restrict__ dip,
    const float* __restrict__ quad,
    f32x4* __restrict__ table,        // [N,2] 16B words
    int N)
{
    int i = blockIdx.x * blockDim.x + threadIdx.x;
    if (i >= N) return;
    const float* dp = dip + 3 * (size_t)i;
    const float* qp = quad + 9 * (size_t)i;

    f32x4 w0 = {q[i], dp[0], dp[1], dp[2]};

    float q00 = qp[0], q01 = qp[1], q02 = qp[2];
    float q10 = qp[3], q11 = qp[4], q12 = qp[5];
    float q20 = qp[6], q21 = qp[7], q22 = qp[8];
    float trQ3 = (q00 + q11 + q22) * (1.0f / 3.0f);

    u32x4 w1 = {pack_h2(q00 - trQ3, q11 - trQ3),
                pack_h2(q22 - trQ3, q01 + q10),
                pack_h2(q02 + q20, q12 + q21),
                0u};

    table[2 * (size_t)i + 0] = w0;
    table[2 * (size_t)i + 1] = __builtin_bit_cast(f32x4, w1);
}

__device__ __forceinline__ float edge_energy(
    float vx, float vy, float vz,
    f32x4 au, f32x4 av, f32x4 bqf)
{
    u32x4 bv = __builtin_bit_cast(u32x4, bqf);

    float d2 = vx * vx + vy * vy + vz * vz;
    float inv_d = __builtin_amdgcn_rsqf(d2);     // 1/|v|, ~1ulp
    float d = d2 * inv_d;
    float inv_d2 = inv_d * inv_d;

    // poly5 switch, cutoff_sr = 4
    float x = d * 0.25f;
    float x2 = x * x;
    float x3 = x2 * x;
    float sw = 1.0f - x3 * (10.0f - 15.0f * x + 6.0f * x2);
    sw = (x < 1.0f) ? sw : 0.0f;
    float chi = sw * __builtin_amdgcn_rsqf(d2 + 1.0f) + (1.0f - sw) * inv_d;

    // shifted-force corrections (cutoff = 10)
    float c1 = chi - (0.2f   - 0.01f   * d);
    float chi2 = chi * chi;
    float chi3 = chi2 * chi;
    float c2 = chi2 - (0.03f  - 0.002f  * d);
    float c3 = chi3 - (0.004f - 0.0003f * d);

    float qu = au.x, qv = av.x;
    float Ee = qu * qv * c1;

    float dot_uv = (vx * av.y + vy * av.z + vz * av.w) * inv_d;
    float dot_vu = (vx * au.y + vy * au.z + vz * au.w) * inv_d;
    float dd     = au.y * av.y + au.z * av.z + au.w * av.w;

    Ee += 2.0f * qu * dot_uv * c2;
    Ee += (dd - 3.0f * dot_uv * dot_vu) * c3;

    // traceless quadrupole contraction (uses sum(v_i^2) == d^2)
    float2 h0 = unpack_h2(bv.x);   // t00, t11
    float2 h1 = unpack_h2(bv.y);   // t22, s01
    float2 h2 = unpack_h2(bv.z);   // s02, s12
    float num = h0.x * vx * vx + h0.y * vy * vy + h1.x * vz * vz
              + h1.y * vx * vy + h2.x * vx * vz + h2.y * vy * vz;
    Ee += qu * (num * inv_d2) * c3;

    Ee *= KEHALF;
    return (d <= 10.0f) ? Ee : 0.0f;
}

__global__ __launch_bounds__(256) void damped_elec_g2s4(
    const f32x4* __restrict__ table,  // [N,2]
    const float* __restrict__ vec,    // [E,3]
    const int*   __restrict__ idx_u,  // [E]
    const int*   __restrict__ idx_v,  // [E]
    float*       __restrict__ out,    // [E]
    int E)
{
    const int tid = blockIdx.x * blockDim.x + threadIdx.x;
    const int S = gridDim.x * blockDim.x;
    if (tid >= E) return;

    const size_t last = (size_t)E - 1;
    const int n = (E - 1 - tid) / S;          // edges owned = n+1

    size_t iA = tid;
    size_t iB = iA + S; if (iB > last) iB = last;
    size_t iC = iB + S; if (iC > last) iC = last;
    size_t iD = iC + S; if (iD > last) iD = last;

    // ---- prologue: 4 stream stages ----
    int   u0 = NTL(idx_u + iA), v0 = NTL(idx_v + iA);
    float xA = NTL(vec + 3 * iA + 0), yA = NTL(vec + 3 * iA + 1), zA = NTL(vec + 3 * iA + 2);
    int   u1 = NTL(idx_u + iB), v1 = NTL(idx_v + iB);
    float xB = NTL(vec + 3 * iB + 0), yB = NTL(vec + 3 * iB + 1), zB = NTL(vec + 3 * iB + 2);
    int   uC = NTL(idx_u + iC), vC = NTL(idx_v + iC);
    float xC = NTL(vec + 3 * iC + 0), yC = NTL(vec + 3 * iC + 1), zC = NTL(vec + 3 * iC + 2);
    int   uD = NTL(idx_u + iD), vD = NTL(idx_v + iD);
    float xD = NTL(vec + 3 * iD + 0), yD = NTL(vec + 3 * iD + 1), zD = NTL(vec + 3 * iD + 2);

    // ---- prologue: 2 gather stages (edges k, k+1) ----
    f32x4 auA = table[2 * (size_t)u0];
    f32x4 avA = table[2 * (size_t)v0 + 0];
    f32x4 qA  = table[2 * (size_t)v0 + 1];
    f32x4 auB = table[2 * (size_t)u1];
    f32x4 avB = table[2 * (size_t)v1 + 0];
    f32x4 qB  = table[2 * (size_t)v1 + 1];

    size_t i  = iA;          // current edge
    size_t iP = iD + S;      // stream prefetch index (k+4)

    for (int k = 0; k <= n; ++k) {
        if (iP > last) iP = last;

        // 1) streams for edge k+4 (consumed 4 iterations later)
        int   uE = NTL(idx_u + iP), vE = NTL(idx_v + iP);
        float xE = NTL(vec + 3 * iP + 0), yE = NTL(vec + 3 * iP + 1), zE = NTL(vec + 3 * iP + 2);

        // 2) gathers for edge k+2 (idx resident 2 iters; consumed 2 iters later)
        f32x4 auC = table[2 * (size_t)uC];
        f32x4 avC = table[2 * (size_t)vC + 0];
        f32x4 qC  = table[2 * (size_t)vC + 1];

        // 3) compute edge k — its gathers are 2 full iterations old
        float r = edge_energy(xA, yA, zA, auA, avA, qA);
        __builtin_nontemporal_store(r, out + i);

        // rotate pipeline
        i += S;
        xA = xB; yA = yB; zA = zB;  auA = auB; avA = avB; qA = qB;
        xB = xC; yB = yC; zB = zC;  auB = auC; avB = avC; qB = qC;
        uC = uD; vC = vD; xC = xD; yC = yD; zC = zD;
        uD = uE; vD = vE; xD = xE; yD = yE; zD = zE;
        iP += S;
    }
}

// Fallback if ws_size is too small for the packed table.
__global__ __launch_bounds__(256) void damped_elec_unpacked(
    const float* __restrict__ q,
    const float* __restrict__ dip,
    const float* __restrict__ quad,
    const float* __restrict__ vec,
    const int*   __restrict__ idx_u,
    const int*   __restrict__ idx_v,
    float*       __restrict__ out,
    int E)
{
    int i = blockIdx.x * blockDim.x + threadIdx.x;
    if (i >= E) return;
    float vx = vec[3 * (size_t)i + 0];
    float vy = vec[3 * (size_t)i + 1];
    float vz = vec[3 * (size_t)i + 2];
    int u = idx_u[i];
    int v = idx_v[i];
    const float* pu = dip + 3 * (size_t)u;
    const float* pv = dip + 3 * (size_t)v;
    const float* pq = quad + 9 * (size_t)v;

    f32x4 au = {q[u], pu[0], pu[1], pu[2]};
    f32x4 av = {q[v], pv[0], pv[1], pv[2]};
    float trQ3 = (pq[0] + pq[4] + pq[8]) * (1.0f / 3.0f);
    u32x4 bv = {pack_h2(pq[0] - trQ3, pq[4] - trQ3),
                pack_h2(pq[8] - trQ3, pq[1] + pq[3]),
                pack_h2(pq[2] + pq[6], pq[5] + pq[7]),
                0u};
    out[i] = edge_energy(vx, vy, vz, au, av, __builtin_bit_cast(f32x4, bv));
}

extern "C" void kernel_launch(void* const* d_in, const int* in_sizes, int n_in,
                              void* d_out, int out_size, void* d_ws, size_t ws_size,
                              hipStream_t stream) {
    const float* q    = (const float*)d_in[0];  // atomic_charges      [N]
    const float* dip  = (const float*)d_in[1];  // atomic_dipoles      [N,3]
    const float* quad = (const float*)d_in[2];  // atomic_quadrupoles  [N,3,3]
    const float* vec  = (const float*)d_in[3];  // vectors_uv          [E,3]
    const int*   iu   = (const int*)d_in[5];    // idx_u               [E]
    const int*   iv   = (const int*)d_in[6];    // idx_v               [E]
    float* out = (float*)d_out;

    int N = in_sizes[0];
    int E = in_sizes[4];
    int block = 256;

    size_t need = (size_t)N * 32;
    if (ws_size >= need) {
        f32x4* table = (f32x4*)d_ws;
        int pgrid = (N + block - 1) / block;
        pack_atoms_kernel<<<pgrid, block, 0, stream>>>(q, dip, quad, table, N);
        // 2048 blocks x 256: ~6 edges/thread, deep enough to amortize the
        // 4-stage prologue; low VGPR keeps ~6-8 waves/SIMD resident.
        damped_elec_g2s4<<<2048, block, 0, stream>>>(table, vec, iu, iv, out, E);
    } else {
        int egrid = (E + block - 1) / block;
        damped_elec_unpacked<<<egrid, block, 0, stream>>>(q, dip, quad, vec, iu, iv, out, E);
    }
}

// Round 13
// 56.264 us; speedup vs baseline: 1.0321x; 1.0321x over previous
//
#include <hip/hip_runtime.h>
#include <hip/hip_fp16.h>

// Damped electrostatics with shifted-force cutoff.
// Packed atom table in d_ws, 32 B/atom (3.2 MB, L2-resident per XCD):
//   word0 (f32x4): q, dip.x, dip.y, dip.z
//   word1 (u32x4): fp16x2{t00,t11}, fp16x2{t22,s01}, fp16x2{s02,s12}, pad
// Edge kernel: grid-stride, next iteration's stream loads (idx/vec, nt)
// issued while the current iteration's gathers are consumed.
// Per edge: 2 unique cache-line touches (atom u, atom v) — the structural
// minimum; the kernel runs at the divergent-gather miss-throughput cap.
// d recomputed from vec (d == |v| by construction).

#define CUTOFF      10.0f
#define KEHALF      7.199822675975274f

typedef float    f32x4 __attribute__((ext_vector_type(4)));
typedef unsigned u32x4 __attribute__((ext_vector_type(4)));

__device__ __forceinline__ unsigned pack_h2(float a, float b) {
    return __builtin_bit_cast(unsigned, __floats2half2_rn(a, b));
}
__device__ __forceinline__ float2 unpack_h2(unsigned u) {
    return __half22float2(__builtin_bit_cast(__half2, u));
}

__global__ __launch_bounds__(256) void pack_atoms_kernel(
    const float* __restrict__ q,
    const float* __restrict__ dip,
    const float* __restrict__ quad,
    f32x4* __restrict__ table,        // [N,2] 16B words
    int N)
{
    int i = blockIdx.x * blockDim.x + threadIdx.x;
    if (i >= N) return;
    const float* dp = dip + 3 * (size_t)i;
    const float* qp = quad + 9 * (size_t)i;

    f32x4 w0 = {q[i], dp[0], dp[1], dp[2]};

    float q00 = qp[0], q01 = qp[1], q02 = qp[2];
    float q10 = qp[3], q11 = qp[4], q12 = qp[5];
    float q20 = qp[6], q21 = qp[7], q22 = qp[8];
    float trQ3 = (q00 + q11 + q22) * (1.0f / 3.0f);

    u32x4 w1 = {pack_h2(q00 - trQ3, q11 - trQ3),
                pack_h2(q22 - trQ3, q01 + q10),
                pack_h2(q02 + q20, q12 + q21),
                0u};

    table[2 * (size_t)i + 0] = w0;
    table[2 * (size_t)i + 1] = __builtin_bit_cast(f32x4, w1);
}

__device__ __forceinline__ float edge_energy(
    float vx, float vy, float vz,
    f32x4 au, f32x4 av, u32x4 bv)
{
    float d2 = vx * vx + vy * vy + vz * vz;
    float d = sqrtf(d2);
    float inv_d = 1.0f / d;
    float inv_d2 = inv_d * inv_d;

    // poly5 switch, cutoff_sr = 4
    float x = d * 0.25f;
    float x2 = x * x;
    float x3 = x2 * x;
    float sw = 1.0f - x3 * (10.0f - 15.0f * x + 6.0f * x2);
    sw = (x < 1.0f) ? sw : 0.0f;
    float chi = sw * rsqrtf(d2 + 1.0f) + (1.0f - sw) * inv_d;

    // shifted-force corrections (cutoff = 10)
    float c1 = chi - (0.2f   - 0.01f   * d);
    float chi2 = chi * chi;
    float chi3 = chi2 * chi;
    float c2 = chi2 - (0.03f  - 0.002f  * d);
    float c3 = chi3 - (0.004f - 0.0003f * d);

    float qu = au.x, qv = av.x;
    float Ee = qu * qv * c1;

    float dot_uv = (vx * av.y + vy * av.z + vz * av.w) * inv_d;
    float dot_vu = (vx * au.y + vy * au.z + vz * au.w) * inv_d;
    float dd     = au.y * av.y + au.z * av.z + au.w * av.w;

    Ee += 2.0f * qu * dot_uv * c2;
    Ee += (dd - 3.0f * dot_uv * dot_vu) * c3;

    // traceless quadrupole contraction (uses sum(v_i^2) == d^2)
    float2 h0 = unpack_h2(bv.x);   // t00, t11
    float2 h1 = unpack_h2(bv.y);   // t22, s01
    float2 h2 = unpack_h2(bv.z);   // s02, s12
    float num = h0.x * vx * vx + h0.y * vy * vy + h1.x * vz * vz
              + h1.y * vx * vy + h2.x * vx * vz + h2.y * vy * vz;
    Ee += qu * (num * inv_d2) * c3;

    Ee *= KEHALF;
    return (d <= CUTOFF) ? Ee : 0.0f;
}

__global__ __launch_bounds__(256) void damped_elec_pipe(
    const f32x4* __restrict__ table,  // [N,2]
    const float* __restrict__ vec,    // [E,3]
    const int*   __restrict__ idx_u,  // [E]
    const int*   __restrict__ idx_v,  // [E]
    float*       __restrict__ out,    // [E]
    int E)
{
    int tid = blockIdx.x * blockDim.x + threadIdx.x;
    int stride = gridDim.x * blockDim.x;

    size_t i = tid;
    if (i >= (size_t)E) return;

    // ---- prologue: streams for the first edge ----
    int u = __builtin_nontemporal_load(idx_u + i);
    int v = __builtin_nontemporal_load(idx_v + i);
    float vx = __builtin_nontemporal_load(vec + 3 * i + 0);
    float vy = __builtin_nontemporal_load(vec + 3 * i + 1);
    float vz = __builtin_nontemporal_load(vec + 3 * i + 2);

    for (;;) {
        size_t inext = i + (size_t)stride;
        bool more = inext < (size_t)E;

        // 1) issue gathers for the CURRENT edge (idx already resident)
        f32x4 au = table[2 * (size_t)u];
        f32x4 av = table[2 * (size_t)v + 0];
        f32x4 bq = table[2 * (size_t)v + 1];

        // 2) issue NEXT edge's streams — independent, stay in flight
        //    through the compute below
        int un = 0, vn = 0;
        float nx = 0.f, ny = 0.f, nz = 0.f;
        if (more) {
            un = __builtin_nontemporal_load(idx_u + inext);
            vn = __builtin_nontemporal_load(idx_v + inext);
            nx = __builtin_nontemporal_load(vec + 3 * inext + 0);
            ny = __builtin_nontemporal_load(vec + 3 * inext + 1);
            nz = __builtin_nontemporal_load(vec + 3 * inext + 2);
        }

        // 3) compute current edge (waits only on the gathers)
        float r = edge_energy(vx, vy, vz, au, av, __builtin_bit_cast(u32x4, bq));
        __builtin_nontemporal_store(r, out + i);

        if (!more) break;
        i = inext;
        u = un; v = vn; vx = nx; vy = ny; vz = nz;
    }
}

// Fallback if ws_size is too small for the packed table.
__global__ __launch_bounds__(256) void damped_elec_unpacked(
    const float* __restrict__ q,
    const float* __restrict__ dip,
    const float* __restrict__ quad,
    const float* __restrict__ vec,
    const int*   __restrict__ idx_u,
    const int*   __restrict__ idx_v,
    float*       __restrict__ out,
    int E)
{
    int i = blockIdx.x * blockDim.x + threadIdx.x;
    if (i >= E) return;
    float vx = vec[3 * (size_t)i + 0];
    float vy = vec[3 * (size_t)i + 1];
    float vz = vec[3 * (size_t)i + 2];
    int u = idx_u[i];
    int v = idx_v[i];
    const float* pu = dip + 3 * (size_t)u;
    const float* pv = dip + 3 * (size_t)v;
    const float* pq = quad + 9 * (size_t)v;

    f32x4 au = {q[u], pu[0], pu[1], pu[2]};
    f32x4 av = {q[v], pv[0], pv[1], pv[2]};
    float trQ3 = (pq[0] + pq[4] + pq[8]) * (1.0f / 3.0f);
    u32x4 bv = {pack_h2(pq[0] - trQ3, pq[4] - trQ3),
                pack_h2(pq[8] - trQ3, pq[1] + pq[3]),
                pack_h2(pq[2] + pq[6], pq[5] + pq[7]),
                0u};
    out[i] = edge_energy(vx, vy, vz, au, av, bv);
}

extern "C" void kernel_launch(void* const* d_in, const int* in_sizes, int n_in,
                              void* d_out, int out_size, void* d_ws, size_t ws_size,
                              hipStream_t stream) {
    const float* q    = (const float*)d_in[0];  // atomic_charges      [N]
    const float* dip  = (const float*)d_in[1];  // atomic_dipoles      [N,3]
    const float* quad = (const float*)d_in[2];  // atomic_quadrupoles  [N,3,3]
    const float* vec  = (const float*)d_in[3];  // vectors_uv          [E,3]
    const int*   iu   = (const int*)d_in[5];    // idx_u               [E]
    const int*   iv   = (const int*)d_in[6];    // idx_v               [E]
    float* out = (float*)d_out;

    int N = in_sizes[0];
    int E = in_sizes[4];
    int block = 256;

    size_t need = (size_t)N * 32;
    if (ws_size >= need) {
        f32x4* table = (f32x4*)d_ws;
        int pgrid = (N + block - 1) / block;
        pack_atoms_kernel<<<pgrid, block, 0, stream>>>(q, dip, quad, table, N);
        // 2048 blocks x 256 = 8 blocks/CU; each thread pipelines ~6 edges.
        damped_elec_pipe<<<2048, block, 0, stream>>>(table, vec, iu, iv, out, E);
    } else {
        int egrid = (E + block - 1) / block;
        damped_elec_unpacked<<<egrid, block, 0, stream>>>(q, dip, quad, vec, iu, iv, out, E);
    }
}